// Round 1
// baseline (7055.796 us; speedup 1.0000x reference)
//
#include <hip/hip_runtime.h>

// ============================================================================
// Gemma3 6-layer forward on MI355X (gfx950).
// R1 baseline: all matmuls via split-bf16 MFMA (hi+lo, 3x mfma_16x16x32_bf16,
// fp32 accumulate) => ~fp32 accuracy at bf16-MFMA-rate/3. Elementwise /
// softmax / norms as small fp32 kernels.
// ============================================================================

#define DEV __device__ __forceinline__

typedef float f32x4 __attribute__((ext_vector_type(4)));
typedef __bf16 bf16x8 __attribute__((ext_vector_type(8)));
typedef unsigned short u16x8 __attribute__((ext_vector_type(8)));

constexpr int kT   = 512;    // query tokens
constexpr int kCtx = 1536;   // cached context
constexpr int kS   = 2048;   // total keys
constexpr int kNH  = 8;
constexpr int kHD  = 256;
constexpr int kD   = 2048;
constexpr int kFF  = 6144;
constexpr int kV   = 32000;
constexpr int kQKV = 2560;   // 8*256 q + 256 k + 256 v
constexpr int kL   = 6;
constexpr float kEps = 1e-6f;

// ---------------------------------------------------------------------------
// helpers
// ---------------------------------------------------------------------------
DEV unsigned short f2bf(float f) {           // fp32 -> bf16 (RNE)
    unsigned u = __float_as_uint(f);
    u += 0x7FFFu + ((u >> 16) & 1u);
    return (unsigned short)(u >> 16);
}
DEV float bf2f(unsigned short h) { return __uint_as_float(((unsigned)h) << 16); }

DEV float block_reduce_sum(float v, float* red) {   // 256 threads, 4 waves
    #pragma unroll
    for (int o = 32; o; o >>= 1) v += __shfl_down(v, o, 64);
    if ((threadIdx.x & 63) == 0) red[threadIdx.x >> 6] = v;
    __syncthreads();
    v = red[0] + red[1] + red[2] + red[3];
    __syncthreads();
    return v;
}
DEV float block_reduce_max(float v, float* red) {
    #pragma unroll
    for (int o = 32; o; o >>= 1) v = fmaxf(v, __shfl_down(v, o, 64));
    if ((threadIdx.x & 63) == 0) red[threadIdx.x >> 6] = v;
    __syncthreads();
    v = fmaxf(fmaxf(red[0], red[1]), fmaxf(red[2], red[3]));
    __syncthreads();
    return v;
}
DEV float tanh_fast(float x) {               // tanh via hw exp
    float e = __expf(2.f * x);
    return 1.f - 2.f / (e + 1.f);
}
DEV float gelu_tanh(float x) {               // jax approximate gelu
    float t = 0.7978845608028654f * (x + 0.044715f * x * x * x);
    return 0.5f * x * (1.f + tanh_fast(t));
}

// ---------------------------------------------------------------------------
// split-bf16 GEMM:  C[M,N] = A[M,K] * W[N,K]^T   (fp32 in/out, lda=ldw=K)
// tile 128x128x32, 256 threads (4 waves, 2x2), grid (M/128, N/128, batch)
// ---------------------------------------------------------------------------
#define BM 128
#define BN 128
#define BK 32

DEV void cvt_store16(unsigned short* baseH, unsigned short* baseL, int byteoff,
                     float4 a, float4 b) {
    __builtin_assume((byteoff & 15) == 0);
    float xs[8] = {a.x, a.y, a.z, a.w, b.x, b.y, b.z, b.w};
    u16x8 hv, lv;
    #pragma unroll
    for (int j = 0; j < 8; ++j) {
        unsigned short hb = f2bf(xs[j]);
        hv[j] = hb;
        lv[j] = f2bf(xs[j] - bf2f(hb));
    }
    *(u16x8*)((char*)baseH + byteoff) = hv;
    *(u16x8*)((char*)baseL + byteoff) = lv;
}
DEV bf16x8 lds_frag(const unsigned short* base, int byteoff) {
    __builtin_assume((byteoff & 15) == 0);
    return *(const bf16x8*)((const char*)base + byteoff);
}
// swizzle: 16B slot index XORed with row bits -> frag reads are 2-way (free)
DEV int swz(int row, int slot16) { return row * 64 + ((slot16 * 16) ^ (((row >> 1) & 3) << 4)); }

__global__ __launch_bounds__(256, 2)
void gemm_split_kernel(const float* __restrict__ A, const float* __restrict__ W,
                       float* __restrict__ C, int K, int ldc,
                       long sA, long sW, long sC)
{
    __shared__ __align__(16) unsigned short sAh[BM * BK];
    __shared__ __align__(16) unsigned short sAl[BM * BK];
    __shared__ __align__(16) unsigned short sWh[BN * BK];
    __shared__ __align__(16) unsigned short sWl[BN * BK];

    const int tid = threadIdx.x;
    A += (long)blockIdx.x * BM * K + (long)blockIdx.z * sA;
    W += (long)blockIdx.y * BN * K + (long)blockIdx.z * sW;
    C += (long)blockIdx.x * BM * ldc + (long)blockIdx.y * BN + (long)blockIdx.z * sC;

    const int srow = tid >> 2;          // 0..63 staging row
    const int schk = tid & 3;           // 0..3  staging 8-float chunk
    const int wid  = tid >> 6;
    const int lane = tid & 63;
    const int wr = wid >> 1, wc = wid & 1;
    const int l16 = lane & 15, lk = lane >> 4;

    f32x4 acc[4][4] = {};
    const int nk = K >> 5;

    for (int kt = 0; kt < nk; ++kt) {
        const float* Ak = A + kt * BK;
        const float* Wk = W + kt * BK;
        #pragma unroll
        for (int half = 0; half < 2; ++half) {
            const int row = srow + half * 64;
            const long off = (long)row * K + schk * 8;
            float4 a0 = *(const float4*)(Ak + off);
            float4 a1 = *(const float4*)(Ak + off + 4);
            float4 w0 = *(const float4*)(Wk + off);
            float4 w1 = *(const float4*)(Wk + off + 4);
            const int cb = swz(row, schk);
            cvt_store16(sAh, sAl, cb, a0, a1);
            cvt_store16(sWh, sWl, cb, w0, w1);
        }
        __syncthreads();

        bf16x8 ah[4], al[4], bh[4], bl[4];
        #pragma unroll
        for (int mi = 0; mi < 4; ++mi) {
            const int r = wr * 64 + mi * 16 + l16;
            ah[mi] = lds_frag(sAh, swz(r, lk));
            al[mi] = lds_frag(sAl, swz(r, lk));
        }
        #pragma unroll
        for (int ni = 0; ni < 4; ++ni) {
            const int r = wc * 64 + ni * 16 + l16;
            bh[ni] = lds_frag(sWh, swz(r, lk));
            bl[ni] = lds_frag(sWl, swz(r, lk));
        }
        #pragma unroll
        for (int mi = 0; mi < 4; ++mi)
        #pragma unroll
        for (int ni = 0; ni < 4; ++ni) {
            f32x4 c = acc[mi][ni];
            c = __builtin_amdgcn_mfma_f32_16x16x32_bf16(ah[mi], bh[ni], c, 0, 0, 0);
            c = __builtin_amdgcn_mfma_f32_16x16x32_bf16(ah[mi], bl[ni], c, 0, 0, 0);
            c = __builtin_amdgcn_mfma_f32_16x16x32_bf16(al[mi], bh[ni], c, 0, 0, 0);
            acc[mi][ni] = c;
        }
        __syncthreads();
    }

    // C/D layout (m89-verified): col = lane&15, row = (lane>>4)*4 + reg
    #pragma unroll
    for (int mi = 0; mi < 4; ++mi)
    #pragma unroll
    for (int ni = 0; ni < 4; ++ni)
    #pragma unroll
    for (int j = 0; j < 4; ++j) {
        const int r  = wr * 64 + mi * 16 + lk * 4 + j;
        const int cc = wc * 64 + ni * 16 + l16;
        C[(long)r * ldc + cc] = acc[mi][ni][j];
    }
}

// ---------------------------------------------------------------------------
// small kernels
// ---------------------------------------------------------------------------
__global__ __launch_bounds__(256)
void rmsnorm_kernel(const float* __restrict__ in, const float* __restrict__ w,
                    float* __restrict__ out)       // rows of kD, grid = kT
{
    __shared__ float red[4];
    const long base = (long)blockIdx.x * kD;
    const int i0 = threadIdx.x * 2;
    float4 v0 = ((const float4*)(in + base))[i0];
    float4 v1 = ((const float4*)(in + base))[i0 + 1];
    float ssq = v0.x*v0.x + v0.y*v0.y + v0.z*v0.z + v0.w*v0.w
              + v1.x*v1.x + v1.y*v1.y + v1.z*v1.z + v1.w*v1.w;
    float tot = block_reduce_sum(ssq, red);
    const float sc = rsqrtf(tot / kD + kEps);
    float4 w0 = ((const float4*)w)[i0];
    float4 w1 = ((const float4*)w)[i0 + 1];
    float4 o0, o1;
    o0.x = v0.x * sc * (1.f + w0.x); o0.y = v0.y * sc * (1.f + w0.y);
    o0.z = v0.z * sc * (1.f + w0.z); o0.w = v0.w * sc * (1.f + w0.w);
    o1.x = v1.x * sc * (1.f + w1.x); o1.y = v1.y * sc * (1.f + w1.y);
    o1.z = v1.z * sc * (1.f + w1.z); o1.w = v1.w * sc * (1.f + w1.w);
    ((float4*)(out + base))[i0]     = o0;
    ((float4*)(out + base))[i0 + 1] = o1;
}

__global__ __launch_bounds__(256)
void add_rms_kernel(const float* __restrict__ x, const float* __restrict__ w,
                    float* __restrict__ h)         // h += rms(x, w)
{
    __shared__ float red[4];
    const long base = (long)blockIdx.x * kD;
    const int i0 = threadIdx.x * 2;
    float4 v0 = ((const float4*)(x + base))[i0];
    float4 v1 = ((const float4*)(x + base))[i0 + 1];
    float ssq = v0.x*v0.x + v0.y*v0.y + v0.z*v0.z + v0.w*v0.w
              + v1.x*v1.x + v1.y*v1.y + v1.z*v1.z + v1.w*v1.w;
    float tot = block_reduce_sum(ssq, red);
    const float sc = rsqrtf(tot / kD + kEps);
    float4 w0 = ((const float4*)w)[i0];
    float4 w1 = ((const float4*)w)[i0 + 1];
    float4 h0 = ((float4*)(h + base))[i0];
    float4 h1 = ((float4*)(h + base))[i0 + 1];
    h0.x += v0.x * sc * (1.f + w0.x); h0.y += v0.y * sc * (1.f + w0.y);
    h0.z += v0.z * sc * (1.f + w0.z); h0.w += v0.w * sc * (1.f + w0.w);
    h1.x += v1.x * sc * (1.f + w1.x); h1.y += v1.y * sc * (1.f + w1.y);
    h1.z += v1.z * sc * (1.f + w1.z); h1.w += v1.w * sc * (1.f + w1.w);
    ((float4*)(h + base))[i0]     = h0;
    ((float4*)(h + base))[i0 + 1] = h1;
}

// v-cache: v_full[d][0:1536] = kv_v[d][:]
__global__ __launch_bounds__(256)
void stage_vcache_kernel(const float* __restrict__ src, float* __restrict__ dst)
{
    const int d = blockIdx.x;
    const float4* s4 = (const float4*)(src + (long)d * kCtx);
    float4* d4 = (float4*)(dst + (long)d * kS);
    int idx = threadIdx.x;
    d4[idx] = s4[idx];
    idx += 256;
    if (idx < kCtx / 4) d4[idx] = s4[idx];
}

// per-token QKV postprocess: q/k RMSNorm + RoPE, scatter q/k/v
__global__ __launch_bounds__(256)
void qkv_post_kernel(const float* __restrict__ qkv,
                     const float* __restrict__ qw, const float* __restrict__ kw,
                     const float* __restrict__ cosT, const float* __restrict__ sinT,
                     float* __restrict__ q_all,   // [8][512][256]
                     float* __restrict__ k_full,  // [2048][256] rows 1536+t
                     float* __restrict__ v_full,  // [256][2048] col 1536+t
                     float* __restrict__ k_out,   // [512][256]
                     float* __restrict__ v_out)   // [256][512]
{
    __shared__ float sm[kHD];
    __shared__ float red[4];
    const int t = blockIdx.x, d = threadIdx.x;
    const float* row = qkv + (long)t * kQKV;
    const float c = cosT[t * kHD + d];
    const float s = sinT[t * kHD + d];
    const float qwd = qw[d], kwd = kw[d];

    #pragma unroll 1
    for (int hh = 0; hh < 9; ++hh) {            // 8 q heads then k
        const float xv = row[hh * kHD + d];
        const float ssq = block_reduce_sum(xv * xv, red);
        const float sc = rsqrtf(ssq / kHD + kEps);
        const float n = xv * sc * (1.f + (hh < 8 ? qwd : kwd));
        sm[d] = n;
        __syncthreads();
        const float p = sm[d ^ 128];
        const float xr = (d < 128) ? -p : p;    // rotate-half
        const float o = n * c + xr * s;
        __syncthreads();
        if (hh < 8) q_all[((long)hh * kT + t) * kHD + d] = o;
        else {
            k_full[(long)(kCtx + t) * kHD + d] = o;
            k_out[(long)t * kHD + d] = o;
        }
    }
    const float vv = row[9 * kHD + d];
    v_full[(long)d * kS + (kCtx + t)] = vv;
    v_out[(long)d * kT + t] = vv;
}

// softcap + mask + softmax over rows of kS. grid = kNH*kT, row = h*kT + t
__global__ __launch_bounds__(256)
void softcap_softmax_kernel(float* __restrict__ sc, const float* __restrict__ mask)
{
    __shared__ float red[4];
    const int row = blockIdx.x;
    const int t = row & (kT - 1);
    float* p = sc + (long)row * kS;
    const float* m = mask + (long)t * kS;
    const int base = threadIdx.x * 8;
    float4 x0 = *(const float4*)(p + base);
    float4 x1 = *(const float4*)(p + base + 4);
    float4 m0 = *(const float4*)(m + base);
    float4 m1 = *(const float4*)(m + base + 4);
    float v[8]  = {x0.x, x0.y, x0.z, x0.w, x1.x, x1.y, x1.z, x1.w};
    float mm[8] = {m0.x, m0.y, m0.z, m0.w, m1.x, m1.y, m1.z, m1.w};
    float mx = -3.0e38f;
    #pragma unroll
    for (int j = 0; j < 8; ++j) {
        // raw * (1/16) / 50 = raw * 0.00125 ; cap then mask (ref order)
        float val = 50.f * tanh_fast(v[j] * 0.00125f) + mm[j];
        v[j] = val;
        mx = fmaxf(mx, val);
    }
    mx = block_reduce_max(mx, red);
    float sum = 0.f;
    #pragma unroll
    for (int j = 0; j < 8; ++j) { float e = __expf(v[j] - mx); v[j] = e; sum += e; }
    sum = block_reduce_sum(sum, red);
    const float inv = 1.f / sum;
    x0.x = v[0]*inv; x0.y = v[1]*inv; x0.z = v[2]*inv; x0.w = v[3]*inv;
    x1.x = v[4]*inv; x1.y = v[5]*inv; x1.z = v[6]*inv; x1.w = v[7]*inv;
    *(float4*)(p + base)     = x0;
    *(float4*)(p + base + 4) = x1;
}

__global__ __launch_bounds__(256)
void gelu_mul_kernel(float* __restrict__ g, const float* __restrict__ up)
{
    const long i = ((long)blockIdx.x * 256 + threadIdx.x) * 4;
    float4 x = *(const float4*)(g + i);
    float4 u = *(const float4*)(up + i);
    x.x = gelu_tanh(x.x) * u.x;
    x.y = gelu_tanh(x.y) * u.y;
    x.z = gelu_tanh(x.z) * u.z;
    x.w = gelu_tanh(x.w) * u.w;
    *(float4*)(g + i) = x;
}

// ---------------------------------------------------------------------------
// driver
// ---------------------------------------------------------------------------
extern "C" void kernel_launch(void* const* d_in, const int* in_sizes, int n_in,
                              void* d_out, int out_size, void* d_ws, size_t ws_size,
                              hipStream_t stream)
{
    (void)in_sizes; (void)n_in; (void)out_size; (void)ws_size;
    const float* emb        = (const float*)d_in[0];
    const float* mask_g     = (const float*)d_in[1];
    const float* mask_l     = (const float*)d_in[2];
    const float* cos_g      = (const float*)d_in[3];
    const float* sin_g      = (const float*)d_in[4];
    const float* cos_l      = (const float*)d_in[5];
    const float* sin_l      = (const float*)d_in[6];
    const float* kv_k       = (const float*)d_in[7];
    const float* kv_v       = (const float*)d_in[8];
    const float* w_pre_attn = (const float*)d_in[9];
    const float* w_qkv      = (const float*)d_in[10];
    const float* w_qn       = (const float*)d_in[11];
    const float* w_kn       = (const float*)d_in[12];
    const float* w_out      = (const float*)d_in[13];
    const float* w_post_attn= (const float*)d_in[14];
    const float* w_pre_ff   = (const float*)d_in[15];
    const float* w_w1       = (const float*)d_in[16];
    const float* w_w3       = (const float*)d_in[17];
    const float* w_w2       = (const float*)d_in[18];
    const float* w_post_ff  = (const float*)d_in[19];
    const float* w_final    = (const float*)d_in[20];
    const float* w_lm       = (const float*)d_in[21];

    float* logits = (float*)d_out;                       // [512][32000]
    float* k_out  = logits + (long)kT * kV;              // [6][512][256]
    float* v_out  = k_out + (long)kL * kT * kHD;         // [6][256][512]

    float* ws      = (float*)d_ws;
    float* h_buf   = ws;                                 ws += (long)kT * kD;
    float* x_buf   = ws;                                 ws += (long)kT * kD;
    float* qkv_buf = ws;                                 ws += (long)kT * kQKV;
    float* q_all   = ws;                                 ws += (long)kNH * kT * kHD;
    float* k_full  = ws;                                 ws += (long)kS * kHD;
    float* v_full  = ws;                                 ws += (long)kHD * kS;
    float* scores  = ws;                                 ws += (long)kNH * kT * kS;
    float* ao_buf  = ws;                                 ws += (long)kT * kD;
    float* tmp_buf = ws;                                 ws += (long)kT * kD;
    float* g_buf   = ws;                                 ws += (long)kT * kFF;
    float* up_buf  = ws;                                 ws += (long)kT * kFF;

    hipMemcpyAsync(h_buf, emb, sizeof(float) * (size_t)kT * kD,
                   hipMemcpyDeviceToDevice, stream);

    for (int i = 0; i < kL; ++i) {
        const bool is_local = ((i + 1) % 6 == 0);
        const float* cosT = is_local ? cos_l : cos_g;
        const float* sinT = is_local ? sin_l : sin_g;
        const float* mask = is_local ? mask_l : mask_g;

        rmsnorm_kernel<<<kT, 256, 0, stream>>>(h_buf, w_pre_attn + (long)i * kD, x_buf);
        gemm_split_kernel<<<dim3(4, kQKV / 128, 1), 256, 0, stream>>>(
            x_buf, w_qkv + (long)i * kQKV * kD, qkv_buf, kD, kQKV, 0, 0, 0);

        hipMemcpyAsync(k_full, kv_k + (long)i * kCtx * kHD,
                       sizeof(float) * (size_t)kCtx * kHD,
                       hipMemcpyDeviceToDevice, stream);
        stage_vcache_kernel<<<kHD, 256, 0, stream>>>(kv_v + (long)i * kHD * kCtx, v_full);
        qkv_post_kernel<<<kT, 256, 0, stream>>>(
            qkv_buf, w_qn + (long)i * kHD, w_kn + (long)i * kHD, cosT, sinT,
            q_all, k_full, v_full,
            k_out + (long)i * kT * kHD, v_out + (long)i * kHD * kT);

        // scores[h] = Q_h[512,256] * K_full[2048,256]^T
        gemm_split_kernel<<<dim3(4, kS / 128, kNH), 256, 0, stream>>>(
            q_all, k_full, scores, kHD, kS,
            (long)kT * kHD, 0, (long)kT * kS);
        softcap_softmax_kernel<<<kNH * kT, 256, 0, stream>>>(scores, mask);
        // ao[:, h*256:] = P_h[512,2048] * V_full[256,2048]^T
        gemm_split_kernel<<<dim3(4, kHD / 128, kNH), 256, 0, stream>>>(
            scores, v_full, ao_buf, kS, kNH * kHD,
            (long)kT * kS, 0, (long)kHD);
        gemm_split_kernel<<<dim3(4, kD / 128, 1), 256, 0, stream>>>(
            ao_buf, w_out + (long)i * kD * kD, tmp_buf, kD, kD, 0, 0, 0);
        add_rms_kernel<<<kT, 256, 0, stream>>>(tmp_buf, w_post_attn + (long)i * kD, h_buf);

        rmsnorm_kernel<<<kT, 256, 0, stream>>>(h_buf, w_pre_ff + (long)i * kD, x_buf);
        gemm_split_kernel<<<dim3(4, kFF / 128, 1), 256, 0, stream>>>(
            x_buf, w_w1 + (long)i * kFF * kD, g_buf, kD, kFF, 0, 0, 0);
        gemm_split_kernel<<<dim3(4, kFF / 128, 1), 256, 0, stream>>>(
            x_buf, w_w3 + (long)i * kFF * kD, up_buf, kD, kFF, 0, 0, 0);
        gelu_mul_kernel<<<(kT * kFF / 4) / 256, 256, 0, stream>>>(g_buf, up_buf);
        gemm_split_kernel<<<dim3(4, kD / 128, 1), 256, 0, stream>>>(
            g_buf, w_w2 + (long)i * kD * kFF, tmp_buf, kFF, kD, 0, 0, 0);
        add_rms_kernel<<<kT, 256, 0, stream>>>(tmp_buf, w_post_ff + (long)i * kD, h_buf);
    }

    rmsnorm_kernel<<<kT, 256, 0, stream>>>(h_buf, w_final, x_buf);
    gemm_split_kernel<<<dim3(4, kV / 128, 1), 256, 0, stream>>>(
        x_buf, w_lm, logits, kD, kV, 0, 0, 0);
}